// Round 7
// baseline (302.535 us; speedup 1.0000x reference)
//
#include <hip/hip_runtime.h>

#define NB 10
#define BLOCK 256
#define GRID 4096
#define K 8  // float4-pairs per thread per tile; GRID*BLOCK*K == 2^25/4 exactly

// R6 lesson: nt loads lifted the stream to 3.35 TB/s but the 2-batch-per-thread
// structure serializes batch k+1's loads behind batch k's compute. R7: ONE
// 16-load batch per thread (grid 4096, block-contiguous tiles) -> all loads in
// flight immediately, cross-wave overlap hides everything.
// Accumulators in packed registers (R2/R3: no LDS in hot loop):
//  cnt64/lab64: 10 x 6-bit fields (<=35/segment < 63 for any distribution)
//  rA,rB: 5+5 x 12-bit fixed-point r=round((conf*10-b)*63) (<=2205 < 4095)
// Reconstruction: conf_sum = (b*cnt + rsum/63)/10; quant err ~8e-4 << 4.8e-2.

typedef float vfloat4 __attribute__((ext_vector_type(4)));
typedef int   vint4   __attribute__((ext_vector_type(4)));

__device__ __forceinline__ void acc_one(float xx, unsigned ll,
                                        unsigned long long& cnt64,
                                        unsigned long long& lab64,
                                        unsigned long long& rA,
                                        unsigned long long& rB) {
    float e = __expf(-xx);
    float conf = __builtin_amdgcn_rcpf(1.0f + e);
    float t = conf * 10.0f;
    int b = (int)t;                       // t>=0 so trunc==floor
    b = min(b, NB - 1);
    float r = t - (float)b;
    unsigned rfix = (unsigned)__builtin_fmaf(r, 63.0f, 0.5f);
    int s6 = b * 6;
    cnt64 += 1ULL << s6;
    lab64 += (unsigned long long)ll << s6;
    bool hi = b >= 5;
    int s12 = (hi ? b - 5 : b) * 12;
    unsigned long long val = (unsigned long long)rfix << s12;
    rA += hi ? 0ULL : val;
    rB += hi ? val : 0ULL;
}

__device__ __forceinline__ void flush_packed(unsigned long long& cnt64,
                                             unsigned long long& lab64,
                                             unsigned long long& rA,
                                             unsigned long long& rB,
                                             unsigned* cl, unsigned* ru) {
#pragma unroll
    for (int i = 0; i < NB; ++i) {
        unsigned c = (unsigned)((cnt64 >> (6 * i)) & 63ULL);
        unsigned l = (unsigned)((lab64 >> (6 * i)) & 63ULL);
        cl[i] += c | (l << 16);
    }
#pragma unroll
    for (int i = 0; i < 5; ++i) {
        ru[i]     += (unsigned)((rA >> (12 * i)) & 4095ULL);
        ru[5 + i] += (unsigned)((rB >> (12 * i)) & 4095ULL);
    }
    cnt64 = 0ULL; lab64 = 0ULL; rA = 0ULL; rB = 0ULL;
}

__global__ __launch_bounds__(BLOCK) void ece_partial(const float* __restrict__ logits,
                                                     const int* __restrict__ labels,
                                                     unsigned int* __restrict__ ws,
                                                     int n, int wstride) {
    const int tid = threadIdx.x;
    const int n4 = n >> 2;
    const vfloat4* __restrict__ l4 = (const vfloat4*)logits;
    const vint4*   __restrict__ b4 = (const vint4*)labels;

    unsigned cl[NB], ru[NB];
#pragma unroll
    for (int i = 0; i < NB; ++i) { cl[i] = 0u; ru[i] = 0u; }

    const int TILE = BLOCK * K;  // 2048 vec4 per block
    for (int tbase = blockIdx.x * TILE; tbase < n4; tbase += GRID * TILE) {
        unsigned long long cnt64 = 0ULL, lab64 = 0ULL, rA = 0ULL, rB = 0ULL;
        if (tbase + TILE <= n4) {
            // fast path: all 16 nt loads issued before any compute
            vfloat4 x[K];
            vint4   y[K];
            const int base = tbase + tid;
#pragma unroll
            for (int k = 0; k < K; ++k) x[k] = __builtin_nontemporal_load(&l4[base + k * BLOCK]);
#pragma unroll
            for (int k = 0; k < K; ++k) y[k] = __builtin_nontemporal_load(&b4[base + k * BLOCK]);
#pragma unroll
            for (int k = 0; k < K; ++k) {
#pragma unroll
                for (int j = 0; j < 4; ++j)
                    acc_one(x[k][j], (unsigned)y[k][j], cnt64, lab64, rA, rB);
            }
        } else {
            for (int k = 0; k < K; ++k) {
                int idx = tbase + tid + k * BLOCK;
                if (idx < n4) {
                    vfloat4 x = __builtin_nontemporal_load(&l4[idx]);
                    vint4   yv = __builtin_nontemporal_load(&b4[idx]);
#pragma unroll
                    for (int j = 0; j < 4; ++j)
                        acc_one(x[j], (unsigned)yv[j], cnt64, lab64, rA, rB);
                }
            }
        }
        flush_packed(cnt64, lab64, rA, rB, cl, ru);  // <=32 elems/segment
    }
    // scalar tail (n%4; empty for N=2^25)
    if (blockIdx.x == 0 && tid == 0 && (n & 3)) {
        unsigned long long cnt64 = 0ULL, lab64 = 0ULL, rA = 0ULL, rB = 0ULL;
        for (int j2 = n4 * 4; j2 < n; ++j2)
            acc_one(logits[j2], (unsigned)labels[j2], cnt64, lab64, rA, rB);
        flush_packed(cnt64, lab64, rA, rB, cl, ru);
    }

    // Wave shuffle reduce (exact integer math; cnt field 64*35 < 2^16).
#pragma unroll
    for (int i = 0; i < NB; ++i) {
#pragma unroll
        for (int off = 32; off > 0; off >>= 1) {
            cl[i] += __shfl_down(cl[i], off, 64);
            ru[i] += __shfl_down(ru[i], off, 64);
        }
    }

    __shared__ unsigned red[4][2 * NB];
    const int wave = tid >> 6, lane = tid & 63;
    if (lane == 0) {
#pragma unroll
        for (int i = 0; i < NB; ++i) { red[wave][i] = cl[i]; red[wave][NB + i] = ru[i]; }
    }
    __syncthreads();
    if (tid < 2 * NB) {
        unsigned s = red[0][tid] + red[1][tid] + red[2][tid] + red[3][tid];
        if (tid < NB) {
            atomicAdd(&ws[tid * wstride], s & 0xffffu);       // counts -> 0..9
            atomicAdd(&ws[(NB + tid) * wstride], s >> 16);    // labels -> 10..19
        } else {
            atomicAdd(&ws[(NB + tid) * wstride], s);          // rsum   -> 20..29
        }
    }
}

__global__ void ece_final(const unsigned int* __restrict__ ws, float* __restrict__ out,
                          int wstride) {
    if (threadIdx.x == 0 && blockIdx.x == 0) {
        float ece = 0.0f, mx = 0.0f;
        for (int b = 0; b < NB; ++b) {
            unsigned cnt = ws[b * wstride];
            unsigned lab = ws[(NB + b) * wstride];
            unsigned rs  = ws[(2 * NB + b) * wstride];
            float pos = 0.0f, cfb = 0.0f, e = 0.0f;
            if (cnt > 0u) {
                float inv = 1.0f / (float)cnt;
                pos = (float)lab * inv;
                cfb = ((float)b + (float)rs * (1.0f / 63.0f) * inv) * 0.1f;
                e = fabsf(pos - cfb);
            }
            out[b] = pos;
            out[NB + b] = cfb;
            ece += e;
            mx = fmaxf(mx, e);
        }
        out[2 * NB] = ece;
        out[2 * NB + 1] = mx;
    }
}

extern "C" void kernel_launch(void* const* d_in, const int* in_sizes, int n_in,
                              void* d_out, int out_size, void* d_ws, size_t ws_size,
                              hipStream_t stream) {
    const float* logits = (const float*)d_in[0];
    const int*   labels = (const int*)d_in[1];
    float* out = (float*)d_out;
    unsigned int* ws = (unsigned int*)d_ws;
    int n = in_sizes[0];

    int wstride = (ws_size >= 30 * 16 * sizeof(unsigned)) ? 16 : 1;
    hipMemsetAsync(d_ws, 0, (size_t)(30 * wstride) * sizeof(unsigned), stream);

    ece_partial<<<GRID, BLOCK, 0, stream>>>(logits, labels, ws, n, wstride);
    ece_final<<<1, 64, 0, stream>>>(ws, out, wstride);
}

// Round 8
// 275.624 us; speedup vs baseline: 1.0976x; 1.0976x over previous
//
#include <hip/hip_runtime.h>

#define NB 10
#define BLOCK 256
#define GRID 2048
#define SSTRIDE (GRID * BLOCK)

// R6 (80us, 3.35 TB/s) + straight-line 2-batch pipeline: all 32 nt loads
// issued before any compute (R7 lesson: compiler clamped VGPRs to 52 and
// re-serialized; fixed via __launch_bounds__(256,2) + sched_barrier(0)).
// Accumulators in packed registers (R2/R3: no LDS ops in hot loop):
//  cnt64/lab64: 10 x 6-bit fields (<=32/batch < 63 for any distribution)
//  rA,rB: 5+5 x 12-bit fixed-point r=round((10*conf-b)*63) (<=2016 < 4095)
// Reconstruction: conf_sum = (b*cnt + rsum/63)/10; quant err ~8e-4 << 4.8e-2.

typedef float vfloat4 __attribute__((ext_vector_type(4)));
typedef int   vint4   __attribute__((ext_vector_type(4)));

__device__ __forceinline__ void acc_one(float xx, unsigned ll,
                                        unsigned long long& cnt64,
                                        unsigned long long& lab64,
                                        unsigned long long& rA,
                                        unsigned long long& rB) {
    float e = __expf(-xx);
    float t = __builtin_amdgcn_rcpf(__builtin_fmaf(e, 0.1f, 0.1f));  // 10*sigmoid(x)
    int b = (int)t;                       // t>=0 so trunc==floor
    b = min(b, NB - 1);
    float r = t - (float)b;
    unsigned rfix = (unsigned)__builtin_fmaf(r, 63.0f, 0.5f);
    int s6 = b * 6;
    cnt64 += 1ULL << s6;
    lab64 += (unsigned long long)ll << s6;
    bool hi = b >= 5;
    int s12 = (hi ? b - 5 : b) * 12;
    unsigned long long val = (unsigned long long)rfix << s12;
    rA += hi ? 0ULL : val;
    rB += hi ? val : 0ULL;
}

__device__ __forceinline__ void flush_packed(unsigned long long& cnt64,
                                             unsigned long long& lab64,
                                             unsigned long long& rA,
                                             unsigned long long& rB,
                                             unsigned* cl, unsigned* ru) {
#pragma unroll
    for (int i = 0; i < NB; ++i) {
        unsigned c = (unsigned)((cnt64 >> (6 * i)) & 63ULL);
        unsigned l = (unsigned)((lab64 >> (6 * i)) & 63ULL);
        cl[i] += c | (l << 16);
    }
#pragma unroll
    for (int i = 0; i < 5; ++i) {
        ru[i]     += (unsigned)((rA >> (12 * i)) & 4095ULL);
        ru[5 + i] += (unsigned)((rB >> (12 * i)) & 4095ULL);
    }
    cnt64 = 0ULL; lab64 = 0ULL; rA = 0ULL; rB = 0ULL;
}

__global__ __launch_bounds__(BLOCK, 2) void ece_partial(const float* __restrict__ logits,
                                                        const int* __restrict__ labels,
                                                        unsigned int* __restrict__ ws,
                                                        int n, int wstride) {
    const int tid = threadIdx.x;
    const int gtid = blockIdx.x * BLOCK + tid;
    const int n4 = n >> 2;
    const vfloat4* __restrict__ l4 = (const vfloat4*)logits;
    const vint4*   __restrict__ b4 = (const vint4*)labels;

    unsigned cl[NB], ru[NB];
#pragma unroll
    for (int i = 0; i < NB; ++i) { cl[i] = 0u; ru[i] = 0u; }

    if (n4 == 16 * SSTRIDE) {
        // fast path (N=2^25): exactly 16 vec4 per thread, no bounds checks.
        vfloat4 x0[8], x1[8];
        vint4   y0[8], y1[8];
#pragma unroll
        for (int j = 0; j < 8; ++j) x0[j] = __builtin_nontemporal_load(&l4[gtid + j * SSTRIDE]);
#pragma unroll
        for (int j = 0; j < 8; ++j) y0[j] = __builtin_nontemporal_load(&b4[gtid + j * SSTRIDE]);
#pragma unroll
        for (int j = 0; j < 8; ++j) x1[j] = __builtin_nontemporal_load(&l4[gtid + (8 + j) * SSTRIDE]);
#pragma unroll
        for (int j = 0; j < 8; ++j) y1[j] = __builtin_nontemporal_load(&b4[gtid + (8 + j) * SSTRIDE]);
        __builtin_amdgcn_sched_barrier(0);  // keep all 32 loads above compute

        unsigned long long cnt64 = 0ULL, lab64 = 0ULL, rA = 0ULL, rB = 0ULL;
#pragma unroll
        for (int j = 0; j < 8; ++j) {
#pragma unroll
            for (int k = 0; k < 4; ++k)
                acc_one(x0[j][k], (unsigned)y0[j][k], cnt64, lab64, rA, rB);
        }
        flush_packed(cnt64, lab64, rA, rB, cl, ru);
#pragma unroll
        for (int j = 0; j < 8; ++j) {
#pragma unroll
            for (int k = 0; k < 4; ++k)
                acc_one(x1[j][k], (unsigned)y1[j][k], cnt64, lab64, rA, rB);
        }
        flush_packed(cnt64, lab64, rA, rB, cl, ru);
    } else {
        // generic fallback (never taken for N=2^25)
        for (int v = gtid; v < n4; v += SSTRIDE) {
            unsigned long long cnt64 = 0ULL, lab64 = 0ULL, rA = 0ULL, rB = 0ULL;
            vfloat4 x = __builtin_nontemporal_load(&l4[v]);
            vint4   y = __builtin_nontemporal_load(&b4[v]);
#pragma unroll
            for (int k = 0; k < 4; ++k)
                acc_one(x[k], (unsigned)y[k], cnt64, lab64, rA, rB);
            flush_packed(cnt64, lab64, rA, rB, cl, ru);
        }
        if (gtid == 0 && (n & 3)) {
            unsigned long long cnt64 = 0ULL, lab64 = 0ULL, rA = 0ULL, rB = 0ULL;
            for (int j2 = n4 * 4; j2 < n; ++j2)
                acc_one(logits[j2], (unsigned)labels[j2], cnt64, lab64, rA, rB);
            flush_packed(cnt64, lab64, rA, rB, cl, ru);
        }
    }

    // Wave shuffle reduce (exact integer math; cnt per thread <= 64, so
    // 64-lane sums < 2^13 per halfword; ru < 64*4032 << 2^32).
#pragma unroll
    for (int i = 0; i < NB; ++i) {
#pragma unroll
        for (int off = 32; off > 0; off >>= 1) {
            cl[i] += __shfl_down(cl[i], off, 64);
            ru[i] += __shfl_down(ru[i], off, 64);
        }
    }

    __shared__ unsigned red[4][2 * NB];
    const int wave = tid >> 6, lane = tid & 63;
    if (lane == 0) {
#pragma unroll
        for (int i = 0; i < NB; ++i) { red[wave][i] = cl[i]; red[wave][NB + i] = ru[i]; }
    }
    __syncthreads();
    if (tid < 2 * NB) {
        unsigned s = red[0][tid] + red[1][tid] + red[2][tid] + red[3][tid];
        if (tid < NB) {
            atomicAdd(&ws[tid * wstride], s & 0xffffu);       // counts -> 0..9
            atomicAdd(&ws[(NB + tid) * wstride], s >> 16);    // labels -> 10..19
        } else {
            atomicAdd(&ws[(NB + tid) * wstride], s);          // rsum   -> 20..29
        }
    }
}

__global__ void ece_final(const unsigned int* __restrict__ ws, float* __restrict__ out,
                          int wstride) {
    if (threadIdx.x == 0 && blockIdx.x == 0) {
        float ece = 0.0f, mx = 0.0f;
        for (int b = 0; b < NB; ++b) {
            unsigned cnt = ws[b * wstride];
            unsigned lab = ws[(NB + b) * wstride];
            unsigned rs  = ws[(2 * NB + b) * wstride];
            float pos = 0.0f, cfb = 0.0f, e = 0.0f;
            if (cnt > 0u) {
                float inv = 1.0f / (float)cnt;
                pos = (float)lab * inv;
                cfb = ((float)b + (float)rs * (1.0f / 63.0f) * inv) * 0.1f;
                e = fabsf(pos - cfb);
            }
            out[b] = pos;
            out[NB + b] = cfb;
            ece += e;
            mx = fmaxf(mx, e);
        }
        out[2 * NB] = ece;
        out[2 * NB + 1] = mx;
    }
}

extern "C" void kernel_launch(void* const* d_in, const int* in_sizes, int n_in,
                              void* d_out, int out_size, void* d_ws, size_t ws_size,
                              hipStream_t stream) {
    const float* logits = (const float*)d_in[0];
    const int*   labels = (const int*)d_in[1];
    float* out = (float*)d_out;
    unsigned int* ws = (unsigned int*)d_ws;
    int n = in_sizes[0];

    int wstride = (ws_size >= 30 * 16 * sizeof(unsigned)) ? 16 : 1;
    hipMemsetAsync(d_ws, 0, (size_t)(30 * wstride) * sizeof(unsigned), stream);

    ece_partial<<<GRID, BLOCK, 0, stream>>>(logits, labels, ws, n, wstride);
    ece_final<<<1, 64, 0, stream>>>(ws, out, wstride);
}